// Round 3
// baseline (289.723 us; speedup 1.0000x reference)
//
#include <hip/hip_runtime.h>

typedef float  f32x4  __attribute__((ext_vector_type(4)));
typedef short  bf16x8 __attribute__((ext_vector_type(8)));

#define NT      16384              // BATCH*SEQ tokens
#define NBLOCK  512                // 512 blocks x 4 waves = 2048 waves
#define WPB     4
#define NSTREAM (NBLOCK * WPB)     // 2048 streams
#define TPS     (NT / NSTREAM)     // 8 tokens per wave, contiguous

__device__ __forceinline__ short f2bf(float x) {
  unsigned u = __builtin_bit_cast(unsigned, x);
  u = (u + 0x7FFFu + ((u >> 16) & 1u)) >> 16;   // RNE
  return (short)u;
}

__global__ __launch_bounds__(256, 2) void kron_kernel(const float* __restrict__ x,
                                                      const float* __restrict__ A,
                                                      const float* __restrict__ B,
                                                      const float* __restrict__ bias,
                                                      float* __restrict__ out) {
  // Only the operand fragment tables live in LDS (32KB) -> 8 waves/CU.
  __shared__ bf16x8 AT[1024];   // [s*8+ot*2+c][lane], sigma2-permuted
  __shared__ bf16x8 BT[1024];   // [s*8+pt*2+jc][lane], sigma1 (contiguous k)

  const int lane = threadIdx.x & 63;
  const int w    = threadIdx.x >> 6;
  const int g    = lane >> 4;
  const int l15  = lane & 15;
  const int sid  = blockIdx.x * WPB + w;    // stream id in [0, NSTREAM)

  // Build operand fragment tables cooperatively (each wave builds 4 of 16 rows).
#pragma unroll
  for (int t = 0; t < 4; ++t) {                  // A: idx = s*8 + ot*2 + c
    const int idx = w * 4 + t;
    const int s = idx >> 3, ot = (idx & 7) >> 1, c = idx & 1;
    const int o = ot * 16 + l15;
    bf16x8 v;
#pragma unroll
    for (int e = 0; e < 8; ++e) {
      const int i = c * 32 + 4 * g + (e & 3) + 16 * (e >> 2);   // sigma2
      v[e] = f2bf(A[s * 4096 + o * 64 + i]);
    }
    AT[idx * 64 + lane] = v;
  }
#pragma unroll
  for (int t = 0; t < 4; ++t) {                  // B: idx = s*8 + pt*2 + jc
    const int idx = w * 4 + t;
    const int s = idx >> 3, pt = (idx & 7) >> 1, jc = idx & 1;
    const int p = pt * 16 + l15;
    bf16x8 v;
#pragma unroll
    for (int e = 0; e < 8; ++e) {
      const int j = jc * 32 + 8 * g + e;                        // sigma1
      v[e] = f2bf(B[s * 4096 + p * 64 + j]);
    }
    BT[idx * 64 + lane] = v;
  }
  __syncthreads();

  // X fragments load straight from global: lane (g,l15) reads rows 16*it+l15,
  // cols 32*jc+8g..+7 (32B contiguous). A wave's 64 lanes tile 16 full 128B
  // half-rows per (it,jc) -> perfectly coalesced dwordx4 pairs. No LDS for X.
  const float* xs = x + ((size_t)sid * TPS << 12);

  f32x4 xr[4][2][2];               // next-token fp32 X in flight (64 VGPR)
  auto loadX = [&](int kk) {
    const float* xb = xs + ((size_t)kk << 12);
#pragma unroll
    for (int it = 0; it < 4; ++it)
#pragma unroll
      for (int jc = 0; jc < 2; ++jc) {
        const float* p = xb + (16 * it + l15) * 64 + 32 * jc + 8 * g;
        xr[it][jc][0] = *(const f32x4*)p;
        xr[it][jc][1] = *(const f32x4*)(p + 4);
      }
  };

  bf16x8 xf[4][2];                 // current-token bf16 fragments
  auto convX = [&]() {
#pragma unroll
    for (int it = 0; it < 4; ++it)
#pragma unroll
      for (int jc = 0; jc < 2; ++jc) {
        f32x4 f0 = xr[it][jc][0], f1 = xr[it][jc][1];
        bf16x8 t;
        t[0]=f2bf(f0.x); t[1]=f2bf(f0.y); t[2]=f2bf(f0.z); t[3]=f2bf(f0.w);
        t[4]=f2bf(f1.x); t[5]=f2bf(f1.y); t[6]=f2bf(f1.z); t[7]=f2bf(f1.w);
        xf[it][jc] = t;
      }
  };

  loadX(0);
  convX();

  for (int k = 0; k < TPS; ++k) {
    // Issue next token's loads first; they drain while we run ~64 MFMAs.
    if (k + 1 < TPS) loadX(k + 1);

    f32x4 acc2[4][4];
#pragma unroll
    for (int a = 0; a < 4; ++a)
#pragma unroll
      for (int b = 0; b < 4; ++b)
        acc2[a][b] = (f32x4){0.f, 0.f, 0.f, 0.f};

#pragma unroll
    for (int s = 0; s < 2; ++s) {
      // B fragments (B-op of stage 1)
      bf16x8 bfr[4][2];
#pragma unroll
      for (int pt = 0; pt < 4; ++pt)
#pragma unroll
        for (int jc = 0; jc < 2; ++jc)
          bfr[pt][jc] = BT[(s * 8 + pt * 2 + jc) * 64 + lane];

      // Stage 1: U = X * B_s^T.  D tile (it,pt): lane holds col p=l15, rows i=4g+r.
      f32x4 a1[4][4];
#pragma unroll
      for (int a = 0; a < 4; ++a)
#pragma unroll
        for (int b = 0; b < 4; ++b)
          a1[a][b] = (f32x4){0.f, 0.f, 0.f, 0.f};
#pragma unroll
      for (int it = 0; it < 4; ++it)
#pragma unroll
        for (int pt = 0; pt < 4; ++pt)
#pragma unroll
          for (int jc = 0; jc < 2; ++jc)
            a1[it][pt] = __builtin_amdgcn_mfma_f32_16x16x32_bf16(
                xf[it][jc], bfr[pt][jc], a1[it][pt], 0, 0, 0);

      // Repack U in-lane: stage-2 A-op elem e of chunk c = a1[(e>>2)+2c][pt] reg (e&3).
      bf16x8 uf[4][2];
#pragma unroll
      for (int pt = 0; pt < 4; ++pt)
#pragma unroll
        for (int c = 0; c < 2; ++c) {
          bf16x8 t;
#pragma unroll
          for (int e = 0; e < 8; ++e)
            t[e] = f2bf(a1[(e >> 2) + 2 * c][pt][e & 3]);
          uf[pt][c] = t;
        }

      // A fragments (B-op of stage 2), sigma2 baked into the table.
      bf16x8 afr[4][2];
#pragma unroll
      for (int ot = 0; ot < 4; ++ot)
#pragma unroll
        for (int c = 0; c < 2; ++c)
          afr[ot][c] = AT[(s * 8 + ot * 2 + c) * 64 + lane];

      // Stage 2: Y^T tiles. D tile (pt,ot): lane holds col o=l15, rows p=4g+r.
#pragma unroll
      for (int pt = 0; pt < 4; ++pt)
#pragma unroll
        for (int ot = 0; ot < 4; ++ot)
#pragma unroll
          for (int c = 0; c < 2; ++c)
            acc2[pt][ot] = __builtin_amdgcn_mfma_f32_16x16x32_bf16(
                uf[pt][c], afr[ot][c], acc2[pt][ot], 0, 0, 0);
    }

    // Bias (16KB, L1-resident after first token) + store.
    const int pcol = 4 * g;
    float* ob = out + (((size_t)sid * TPS + k) << 12);
#pragma unroll
    for (int pt = 0; pt < 4; ++pt)
#pragma unroll
      for (int ot = 0; ot < 4; ++ot) {
        const int off = (ot * 16 + l15) * 64 + pt * 16 + pcol;
        f32x4 bv = *(const f32x4*)(bias + off);
        *(f32x4*)(ob + off) = acc2[pt][ot] + bv;
      }

    // Convert next token's X (waits on xr loads issued at iteration start).
    if (k + 1 < TPS) convX();
  }
}

extern "C" void kernel_launch(void* const* d_in, const int* in_sizes, int n_in,
                              void* d_out, int out_size, void* d_ws, size_t ws_size,
                              hipStream_t stream) {
  const float* x    = (const float*)d_in[0];
  const float* A    = (const float*)d_in[1];
  const float* B    = (const float*)d_in[2];
  const float* bias = (const float*)d_in[3];
  float* out        = (float*)d_out;
  kron_kernel<<<dim3(NBLOCK), dim3(256), 0, stream>>>(x, A, B, bias, out);
}

// Round 4
// 118.563 us; speedup vs baseline: 2.4436x; 2.4436x over previous
//
#include <hip/hip_runtime.h>

typedef float  f32x4  __attribute__((ext_vector_type(4)));
typedef short  bf16x8 __attribute__((ext_vector_type(8)));

#define NT      16384              // BATCH*SEQ tokens
#define NBLOCK  256                // 1 block/CU (112KB LDS forces it)
#define WPB     8                  // 8 waves/block -> 2 waves/SIMD
#define NSTREAM (NBLOCK * WPB)     // 2048 streams
#define TPS     (NT / NSTREAM)     // 8 tokens per wave, strided by NSTREAM

__device__ __forceinline__ short f2bf(float x) {
  unsigned u = __builtin_bit_cast(unsigned, x);
  u = (u + 0x7FFFu + ((u >> 16) & 1u)) >> 16;   // RNE
  return (short)u;
}

__device__ __forceinline__ void gload16(const float* gp, float* lp) {
  __builtin_amdgcn_global_load_lds((const __attribute__((address_space(1))) void*)gp,
                                   (__attribute__((address_space(3))) void*)lp,
                                   16, 0, 0);
}

__device__ __forceinline__ unsigned ldsaddr(const void* p) {
  return (unsigned)(uintptr_t)(const __attribute__((address_space(3))) void*)p;
}

// Stage one QUARTER-token (16 rows x 64 cols fp32 = 4KB) via 4 x global_load_lds.
// LDS dest linear; XOR swizzle (16B chunks, chunk ^= row&7) applied to the
// GLOBAL source so the fragment ds_read_b128s are ~conflict-free.
__device__ __forceinline__ void stageQ(float* qb, const float* gbase, int lane) {
#pragma unroll
  for (int q = 0; q < 4; ++q) {
    const int r = q * 4 + (lane >> 4);                        // local row 0..15
    const float* gp = gbase + r * 64 + (((lane & 15) ^ (r & 7)) << 2);
    gload16(gp, qb + q * 256);
  }
}

__global__ __launch_bounds__(512, 2)
void kron_kernel(const float* __restrict__ x,
                 const float* __restrict__ A,
                 const float* __restrict__ Bm,
                 const float* __restrict__ bias,
                 float* __restrict__ out) {
  __shared__ float  xh[WPB][2][1024];  // 64KB: per-wave quarter dbuf (4KB each)
  __shared__ bf16x8 AT[1024];          // 16KB  [s*8+ot*2+c][lane], sigma2 baked
  __shared__ bf16x8 BT[1024];          // 16KB  [s*8+pt*2+jc][lane], sigma1
  __shared__ float  biasl[4096];       // 16KB  bias, fp32

  const int tid  = threadIdx.x;
  const int lane = tid & 63;
  const int w    = tid >> 6;
  const int g    = lane >> 4;
  const int l15  = lane & 15;
  const int sid  = blockIdx.x * WPB + w;   // stream id in [0, NSTREAM)

  // ---- one-time init: tables (2 rows per wave per table) + bias -> LDS ----
#pragma unroll
  for (int t = 0; t < 2; ++t) {
    const int idx = w * 2 + t;
    {  // A table: idx = s*8 + ot*2 + c
      const int s = idx >> 3, ot = (idx & 7) >> 1, c = idx & 1;
      const int o = ot * 16 + l15;
      bf16x8 v;
#pragma unroll
      for (int e = 0; e < 8; ++e) {
        const int i = c * 32 + 4 * g + (e & 3) + 16 * (e >> 2);   // sigma2
        v[e] = f2bf(A[s * 4096 + o * 64 + i]);
      }
      AT[idx * 64 + lane] = v;
    }
    {  // B table: idx = s*8 + pt*2 + jc
      const int s = idx >> 3, pt = (idx & 7) >> 1, jc = idx & 1;
      const int p = pt * 16 + l15;
      bf16x8 v;
#pragma unroll
      for (int e = 0; e < 8; ++e)
        v[e] = f2bf(Bm[s * 4096 + p * 64 + (jc * 32 + 8 * g + e)]); // sigma1
      BT[idx * 64 + lane] = v;
    }
  }
  {  // bias: 512 threads x 8 floats
    const f32x4* b4 = (const f32x4*)bias;
    ((f32x4*)biasl)[tid * 2 + 0] = b4[tid * 2 + 0];
    ((f32x4*)biasl)[tid * 2 + 1] = b4[tid * 2 + 1];
  }
  __syncthreads();

  float* q0b = &xh[w][0][0];
  float* q1b = &xh[w][1][0];
  const unsigned qaddr0 = ldsaddr(q0b);
  const unsigned qaddr1 = ldsaddr(q1b);

  const float* xw = x + ((size_t)sid << 12);

  // Prologue: quarters 0,1 of token 0.
  stageQ(q0b, xw + 0 * 1024, lane);
  stageQ(q1b, xw + 1 * 1024, lane);

  f32x4 acc2[4][4];   // stage-2 accumulators (per token)
  f32x4 a1e[2][4];    // stage-1 tiles of the even quarter, held to the odd one

  for (int k = 0; k < TPS; ++k) {
    const float* xt = xw + ((size_t)k * NSTREAM << 12);
    float* ob = out + (((size_t)k * NSTREAM + sid) << 12);

#pragma unroll
    for (int qq = 0; qq < 4; ++qq) {
      // ---- counted wait: drains this quarter's 4 loads (+older stores),
      // leaves the next quarter's 4 in flight. Only the final phase drains all.
      if (qq == 3 && k == TPS - 1) asm volatile("s_waitcnt vmcnt(0)" ::: "memory");
      else                         asm volatile("s_waitcnt vmcnt(4)" ::: "memory");

      if (qq == 0) {
#pragma unroll
        for (int a = 0; a < 4; ++a)
#pragma unroll
          for (int b = 0; b < 4; ++b)
            acc2[a][b] = (f32x4){0.f, 0.f, 0.f, 0.f};
      }

      // ---- X fragment reads (inline asm: invisible to waitcnt pass) ----
      const unsigned qb = (qq & 1) ? qaddr1 : qaddr0;
      f32x4 r0[2], r1[2];
#pragma unroll
      for (int jc = 0; jc < 2; ++jc) {
        const unsigned q0c  = (unsigned)(8 * jc + 2 * g);
        const unsigned m    = (unsigned)(l15 & 7);
        const unsigned base = qb + (unsigned)l15 * 256u;
        asm volatile("ds_read_b128 %0, %1" : "=v"(r0[jc]) : "v"(base + ((q0c ^ m) * 16u)) : "memory");
        asm volatile("ds_read_b128 %0, %1" : "=v"(r1[jc]) : "v"(base + (((q0c + 1u) ^ m) * 16u)) : "memory");
      }
      asm volatile("s_waitcnt lgkmcnt(0)" ::: "memory");
      __builtin_amdgcn_sched_barrier(0);

      bf16x8 xf[2];
#pragma unroll
      for (int jc = 0; jc < 2; ++jc) {
        bf16x8 tt;
        tt[0]=f2bf(r0[jc][0]); tt[1]=f2bf(r0[jc][1]); tt[2]=f2bf(r0[jc][2]); tt[3]=f2bf(r0[jc][3]);
        tt[4]=f2bf(r1[jc][0]); tt[5]=f2bf(r1[jc][1]); tt[6]=f2bf(r1[jc][2]); tt[7]=f2bf(r1[jc][3]);
        xf[jc] = tt;
      }

      // ---- compute: this quarter is it-tile `qq` (rows 16qq + l15) ----
      if ((qq & 1) == 0) {
        // even quarter: stage-1 tiles only, held in a1e
#pragma unroll
        for (int s = 0; s < 2; ++s) {
#pragma unroll
          for (int pt = 0; pt < 4; ++pt) {
            f32x4 acc = (f32x4){0.f, 0.f, 0.f, 0.f};
#pragma unroll
            for (int jc = 0; jc < 2; ++jc)
              acc = __builtin_amdgcn_mfma_f32_16x16x32_bf16(
                  xf[jc], BT[(s * 8 + pt * 2 + jc) * 64 + lane], acc, 0, 0, 0);
            a1e[s][pt] = acc;
          }
        }
      } else {
        const int c = qq >> 1;   // sigma2 chunk: quarters (0,1)->0, (2,3)->1
#pragma unroll
        for (int s = 0; s < 2; ++s) {
          f32x4 a1o[4];
#pragma unroll
          for (int pt = 0; pt < 4; ++pt) {
            f32x4 acc = (f32x4){0.f, 0.f, 0.f, 0.f};
#pragma unroll
            for (int jc = 0; jc < 2; ++jc)
              acc = __builtin_amdgcn_mfma_f32_16x16x32_bf16(
                  xf[jc], BT[(s * 8 + pt * 2 + jc) * 64 + lane], acc, 0, 0, 0);
            a1o[pt] = acc;
          }
          // repack U in-lane: elem e<4 from even quarter tile, e>=4 from odd
          bf16x8 uf[4];
#pragma unroll
          for (int pt = 0; pt < 4; ++pt) {
            bf16x8 u;
            u[0]=f2bf(a1e[s][pt][0]); u[1]=f2bf(a1e[s][pt][1]);
            u[2]=f2bf(a1e[s][pt][2]); u[3]=f2bf(a1e[s][pt][3]);
            u[4]=f2bf(a1o[pt][0]);    u[5]=f2bf(a1o[pt][1]);
            u[6]=f2bf(a1o[pt][2]);    u[7]=f2bf(a1o[pt][3]);
            uf[pt] = u;
          }
          bf16x8 afr[4];
#pragma unroll
          for (int ot = 0; ot < 4; ++ot)
            afr[ot] = AT[(s * 8 + ot * 2 + c) * 64 + lane];
#pragma unroll
          for (int pt = 0; pt < 4; ++pt)
#pragma unroll
            for (int ot = 0; ot < 4; ++ot)
              acc2[pt][ot] = __builtin_amdgcn_mfma_f32_16x16x32_bf16(
                  uf[pt], afr[ot], acc2[pt][ot], 0, 0, 0);
        }
      }

      // ---- token complete: bias (from LDS) + store; ot outer / pt inner so
      // each 256B output row completes within 4 consecutive instructions ----
      if (qq == 3) {
#pragma unroll
        for (int ot = 0; ot < 4; ++ot)
#pragma unroll
          for (int pt = 0; pt < 4; ++pt) {
            const int off = (ot * 16 + l15) * 64 + pt * 16 + 4 * g;
            f32x4 bv = *(const f32x4*)(biasl + off);
            *(f32x4*)(ob + off) = acc2[pt][ot] + bv;
          }
      }

      // ---- prefetch quarter Q+2 into the buffer just consumed ----
      asm volatile("" ::: "memory");
      if (k < TPS - 1 || qq < 2) {
        const int k2  = (qq >= 2) ? k + 1 : k;
        const int qq2 = (qq + 2) & 3;
        stageQ((qq & 1) ? q1b : q0b,
               xw + ((size_t)k2 * NSTREAM << 12) + qq2 * 1024, lane);
      }
      (void)xt;
    }
  }
}

extern "C" void kernel_launch(void* const* d_in, const int* in_sizes, int n_in,
                              void* d_out, int out_size, void* d_ws, size_t ws_size,
                              hipStream_t stream) {
  const float* x    = (const float*)d_in[0];
  const float* A    = (const float*)d_in[1];
  const float* B    = (const float*)d_in[2];
  const float* bias = (const float*)d_in[3];
  float* out        = (float*)d_out;
  kron_kernel<<<dim3(NBLOCK), dim3(512), 0, stream>>>(x, A, B, bias, out);
}

// Round 5
// 105.231 us; speedup vs baseline: 2.7532x; 1.1267x over previous
//
#include <hip/hip_runtime.h>
#include <hip/hip_bf16.h>

typedef float  f32x4  __attribute__((ext_vector_type(4)));
typedef short  bf16x8 __attribute__((ext_vector_type(8)));

#define NT      16384            // BATCH*SEQ tokens
#define NBLOCK  512              // 1 wave/block, 80KB LDS -> 2 blocks/CU
#define TPS     (NT / NBLOCK)    // 32 tokens per wave, strided by NBLOCK

#define WAITV(n) asm volatile("s_waitcnt vmcnt(" #n ")" ::: "memory")

__device__ __forceinline__ short f2bf(float x) {
  // HW conversion: compiler emits v_cvt_pk_bf16_f32 (RNE).
  return (short)__builtin_bit_cast(unsigned short, __float2bfloat16(x));
}

__device__ __forceinline__ void gload16(const float* gp, float* lp) {
  __builtin_amdgcn_global_load_lds((const __attribute__((address_space(1))) void*)gp,
                                   (__attribute__((address_space(3))) void*)lp,
                                   16, 0, 0);
}

__device__ __forceinline__ unsigned ldsaddr(const void* p) {
  return (unsigned)(uintptr_t)(const __attribute__((address_space(3))) void*)p;
}

// Stage one token's X (64x64 fp32 = 16KB) via 16 x global_load_lds(16B).
// LDS dest linear; XOR swizzle (16B chunks, chunk ^= row&7) applied to the
// GLOBAL source so fragment ds_read_b128s are conflict-free (R1: 0 conflicts).
__device__ __forceinline__ void stage(float* XB, const float* gbase, int lane) {
#pragma unroll
  for (int q = 0; q < 16; ++q) {
    const int i = q * 4 + (lane >> 4);
    const float* gp = gbase + i * 64 + (((lane & 15) ^ (i & 7)) << 2);
    gload16(gp, XB + q * 256);
  }
}

__global__ __launch_bounds__(64, 1)
void kron_kernel(const float* __restrict__ x,
                 const float* __restrict__ A,
                 const float* __restrict__ Bm,
                 const float* __restrict__ bias,
                 float* __restrict__ out) {
  __shared__ float  xh[3][4096];   // 48KB: 3-deep token X buffers
  __shared__ bf16x8 AT[1024];      // 16KB  [s*8+ot*2+c][lane], sigma2 baked
  __shared__ bf16x8 BT[1024];      // 16KB  [s*8+pt*2+jc][lane], sigma1

  const int lane = threadIdx.x;
  const int g    = lane >> 4;
  const int l15  = lane & 15;
  const int bid  = blockIdx.x;

  // ---- one-time: operand fragment tables (single wave, no barrier) ----
  for (int idx = 0; idx < 16; ++idx) {           // A: idx = s*8 + ot*2 + c
    const int s = idx >> 3, ot = (idx & 7) >> 1, c = idx & 1;
    const int o = ot * 16 + l15;
    bf16x8 v;
#pragma unroll
    for (int e = 0; e < 8; ++e) {
      const int i = c * 32 + 4 * g + (e & 3) + 16 * (e >> 2);   // sigma2
      v[e] = f2bf(A[s * 4096 + o * 64 + i]);
    }
    AT[idx * 64 + lane] = v;
  }
  for (int idx = 0; idx < 16; ++idx) {           // B: idx = s*8 + pt*2 + jc
    const int s = idx >> 3, pt = (idx & 7) >> 1, jc = idx & 1;
    const int p = pt * 16 + l15;
    bf16x8 v;
#pragma unroll
    for (int e = 0; e < 8; ++e)
      v[e] = f2bf(Bm[s * 4096 + p * 64 + (jc * 32 + 8 * g + e)]); // sigma1
    BT[idx * 64 + lane] = v;
  }

  // ---- bias -> VGPRs (16 x f32x4); acc2 is initialized from these ----
  const int pcol = 4 * g;
  f32x4 bv[4][4];
#pragma unroll
  for (int pt = 0; pt < 4; ++pt)
#pragma unroll
    for (int ot = 0; ot < 4; ++ot)
      bv[pt][ot] = *(const f32x4*)(bias + (ot * 16 + l15) * 64 + pt * 16 + pcol);

  // ---- prologue: prefetch tokens 0,1 ----
  float* b0 = &xh[0][0];
  float* b1 = &xh[1][0];
  float* b2 = &xh[2][0];
  stage(b0, x + ((size_t)bid << 12), lane);
  stage(b1, x + ((size_t)(bid + NBLOCK) << 12), lane);

  for (int k = 0; k < TPS; ++k) {
    // Queue (oldest->newest) at this point, steady state:
    //   stage(k) | stores(k-2) | stage(k+1) | stores(k-1)   -> W = 48
    // Edges: k=0: only stage(1) newer (W=16); k=1 / k=TPS-1: W=32.
    if (k == 0)                    WAITV(16);
    else if (k == 1 || k == TPS-1) WAITV(32);
    else                           WAITV(48);

    // Prefetch token k+2 into the buffer token k-1 used (issued EARLY so
    // ~32KB of reads stay in flight through the whole body).
    if (k + 2 < TPS)
      stage(b2, x + ((size_t)(bid + (k + 2) * NBLOCK) << 12), lane);

    // ---- X fragment reads (inline asm: invisible to the waitcnt pass) ----
    const unsigned ba = ldsaddr(b0);
    f32x4 r0[4][2], r1[4][2];
#pragma unroll
    for (int it = 0; it < 4; ++it) {
      const unsigned base = ba + (unsigned)(it * 16 + l15) * 256u;
      const unsigned m    = (unsigned)(l15 & 7);
#pragma unroll
      for (int jc = 0; jc < 2; ++jc) {
        const unsigned c0 = (unsigned)(8 * jc + 2 * g);
        asm volatile("ds_read_b128 %0, %1" : "=v"(r0[it][jc]) : "v"(base + ((c0 ^ m) << 4)) : "memory");
        asm volatile("ds_read_b128 %0, %1" : "=v"(r1[it][jc]) : "v"(base + (((c0 + 1u) ^ m) << 4)) : "memory");
      }
    }
    asm volatile("s_waitcnt lgkmcnt(0)" ::: "memory");
    __builtin_amdgcn_sched_barrier(0);

    bf16x8 xf[4][2];
#pragma unroll
    for (int it = 0; it < 4; ++it)
#pragma unroll
      for (int jc = 0; jc < 2; ++jc) {
        bf16x8 t;
        t[0]=f2bf(r0[it][jc][0]); t[1]=f2bf(r0[it][jc][1]);
        t[2]=f2bf(r0[it][jc][2]); t[3]=f2bf(r0[it][jc][3]);
        t[4]=f2bf(r1[it][jc][0]); t[5]=f2bf(r1[it][jc][1]);
        t[6]=f2bf(r1[it][jc][2]); t[7]=f2bf(r1[it][jc][3]);
        xf[it][jc] = t;
      }

    // ---- acc2 = bias (folded init) ----
    f32x4 acc2[4][4];
#pragma unroll
    for (int pt = 0; pt < 4; ++pt)
#pragma unroll
      for (int ot = 0; ot < 4; ++ot)
        acc2[pt][ot] = bv[pt][ot];

#pragma unroll
    for (int s = 0; s < 2; ++s) {
      bf16x8 bfr[4][2];
#pragma unroll
      for (int pt = 0; pt < 4; ++pt)
#pragma unroll
        for (int jc = 0; jc < 2; ++jc)
          bfr[pt][jc] = BT[(s * 8 + pt * 2 + jc) * 64 + lane];

      // Stage 1: U = X * B_s^T.  D tile (it,pt): lane holds col p=l15, rows i=4g+r.
      f32x4 a1[4][4];
#pragma unroll
      for (int a = 0; a < 4; ++a)
#pragma unroll
        for (int b = 0; b < 4; ++b)
          a1[a][b] = (f32x4){0.f, 0.f, 0.f, 0.f};
#pragma unroll
      for (int it = 0; it < 4; ++it)
#pragma unroll
        for (int pt = 0; pt < 4; ++pt)
#pragma unroll
          for (int jc = 0; jc < 2; ++jc)
            a1[it][pt] = __builtin_amdgcn_mfma_f32_16x16x32_bf16(
                xf[it][jc], bfr[pt][jc], a1[it][pt], 0, 0, 0);

      // Repack U in-lane: stage-2 A-op elem e of chunk c = a1[(e>>2)+2c][pt] reg (e&3).
      bf16x8 uf[4][2];
#pragma unroll
      for (int pt = 0; pt < 4; ++pt)
#pragma unroll
        for (int c = 0; c < 2; ++c) {
          bf16x8 t;
#pragma unroll
          for (int e = 0; e < 8; ++e)
            t[e] = f2bf(a1[(e >> 2) + 2 * c][pt][e & 3]);
          uf[pt][c] = t;
        }

      bf16x8 afr[4][2];
#pragma unroll
      for (int ot = 0; ot < 4; ++ot)
#pragma unroll
        for (int c = 0; c < 2; ++c)
          afr[ot][c] = AT[(s * 8 + ot * 2 + c) * 64 + lane];

      // Stage 2: Y^T tiles. D tile (pt,ot): lane holds col o=l15, rows p=4g+r.
#pragma unroll
      for (int pt = 0; pt < 4; ++pt)
#pragma unroll
        for (int ot = 0; ot < 4; ++ot)
#pragma unroll
          for (int c = 0; c < 2; ++c)
            acc2[pt][ot] = __builtin_amdgcn_mfma_f32_16x16x32_bf16(
                uf[pt][c], afr[ot][c], acc2[pt][ot], 0, 0, 0);
    }

    // ---- store (bias already folded into acc2) ----
    float* ob = out + (((size_t)(k * NBLOCK + bid)) << 12);
#pragma unroll
    for (int pt = 0; pt < 4; ++pt)
#pragma unroll
      for (int ot = 0; ot < 4; ++ot)
        *(f32x4*)(ob + (ot * 16 + l15) * 64 + pt * 16 + pcol) = acc2[pt][ot];

    // rotate buffers: k+1 -> b0, k+2 (just staged) -> b1, freed -> b2
    float* t = b0; b0 = b1; b1 = b2; b2 = t;
  }
}

extern "C" void kernel_launch(void* const* d_in, const int* in_sizes, int n_in,
                              void* d_out, int out_size, void* d_ws, size_t ws_size,
                              hipStream_t stream) {
  const float* x    = (const float*)d_in[0];
  const float* A    = (const float*)d_in[1];
  const float* B    = (const float*)d_in[2];
  const float* bias = (const float*)d_in[3];
  float* out        = (float*)d_out;
  kron_kernel<<<dim3(NBLOCK), dim3(64), 0, stream>>>(x, A, B, bias, out);
}